// Round 1
// 282.409 us; speedup vs baseline: 1.0284x; 1.0284x over previous
//
#include <hip/hip_runtime.h>

// EquivariantProductBasisBlock (MACE symmetric contraction, corr=3) + o3.Linear
// N=10000 nodes, C=128 channels, L=9 (lmax=2), E=5 elements, fp32 throughout.
//
// R14 changes vs R13 (contract + table pack only; sort/linear frozen):
//  - FULL (u,v,w) symmetrization of the cubic table: U3 is contracted with
//    x(x)x(x)x, so only the totally symmetric part survives. Table now holds
//    219 coeffs per (e,c,dd): 9 linear + 45 sym-quadratic + 165 sym-cubic,
//    consumed by a triangular Horner (u<=v<=w). 219 FMA per (n,c,dd) vs 495
//    in R13 -> 2.26x less VALU work (pure-FMA floor ~14 us).
//  - Triangular nest fully unrolled -> all x indices compile-time -> XS LDS
//    staging deleted entirely (LDS=0; occupancy no longer LDS-capped).
//  - Thread mapping flipped: 1 node x 4 channels per thread. feats read is
//    144 contiguous 16B-aligned bytes/thread, and each feats byte is read by
//    exactly one block (no 128-way cross-XCD re-read) -> FETCH_SIZE down.
//  - cb coeffs still read directly from global at wave-uniform addresses
//    (f(blockIdx,dd,c) only) -> s_load SMEM path, zero VMEM/LDS cost.

#define CCH 128
#define LDIM 9
#define NE 5
#define BLK 256
#define NCPT 4               // channels per thread in contraction
#define TSTR 220             // coeffs per (e,c,dd): 219 + 1 pad (16B-aligned)
#define TGSTR 880            // per (e,c) = 4*TSTR
#define U3LDS 8748           // staged U3 slice (729*12 max)

// -------------------------------------------- sort: count + offs (fused)
__global__ __launch_bounds__(BLK) void count_offs_kernel(
    const float* __restrict__ attrs, int N,
    int* __restrict__ elem, int* __restrict__ gcnt,   // gcnt[5], gcnt[5]=done
    int* __restrict__ offs, int* __restrict__ cur) {
  int n = blockIdx.x * BLK + threadIdx.x;
  int e = 0;
  if (n < N) {
    const float* a = attrs + n * NE;
#pragma unroll
    for (int j = 1; j < NE; ++j)
      if (a[j] > 0.5f) e = j;
    elem[n] = e;
  }
  int lane = threadIdx.x & 63;
#pragma unroll
  for (int k = 0; k < NE; ++k) {
    unsigned long long m = __ballot(n < N && e == k);
    if (m) {
      int leader = __ffsll((long long)m) - 1;
      if (lane == leader) atomicAdd(&gcnt[k], __popcll(m));
    }
  }
  __threadfence();
  __syncthreads();
  if (threadIdx.x == 0) {
    int t = atomicAdd(&gcnt[NE], 1);
    if (t == (int)gridDim.x - 1) {            // last block: prefix sum
      int acc = 0;
      for (int k = 0; k < NE; ++k) {
        int ck = atomicAdd(&gcnt[k], 0);      // coherent read
        offs[k] = acc; cur[k] = acc; acc += ck;
      }
      offs[NE] = acc;
    }
  }
}

// ----------------------------------------------------------- sort: scatter
__global__ __launch_bounds__(BLK) void scatter_kernel(
    const int* __restrict__ elem, int N,
    int* __restrict__ cur, int* __restrict__ order) {
  int n = blockIdx.x * BLK + threadIdx.x;
  if (n >= N) return;
  int e = elem[n];
  int lane = threadIdx.x & 63;
#pragma unroll
  for (int k = 0; k < NE; ++k) {
    if (e == k) {
      unsigned long long m = __ballot(1);
      int cnt = __popcll(m);
      int leader = __ffsll((long long)m) - 1;
      int base = 0;
      if (lane == leader) base = atomicAdd(&cur[k], cnt);
      base = __shfl(base, leader);
      int rank = __popcll(m & ((1ull << lane) - 1ull));
      order[base + rank] = n;
    }
  }
}

// ---- build + FULLY (u,v,w)-symmetrize + pack U(x)w tables (one dd/block)
__global__ __launch_bounds__(BLK) void table_kernel(
    const float* __restrict__ U3_0, const float* __restrict__ U2_0,
    const float* __restrict__ U1_0, const float* __restrict__ U3_1,
    const float* __restrict__ U2_1, const float* __restrict__ U1_1,
    const float* __restrict__ w3_0, const float* __restrict__ w2_0,
    const float* __restrict__ w1_0, const float* __restrict__ w3_1,
    const float* __restrict__ w2_1, const float* __restrict__ w1_1,
    float* __restrict__ table) {
  const int b = blockIdx.x;        // e*CCH + c
  const int dd = blockIdx.y;       // 0..3
  const int e = b / CCH, c = b % CCH;
  float* Tg = table + (size_t)b * TGSTR + dd * TSTR;
  __shared__ float Us[U3LDS];      // raw U3 slice [729*K3]
  __shared__ float U2s[324];       // raw U2 slice [81*K2]
  __shared__ float R3[729];        // rect T3
  __shared__ float R2[81];
  __shared__ float R1l[9];
  __shared__ float w3l[12], w2l[4];
  const int tid = threadIdx.x;
  const int d = dd - 1;
  const int K3 = (dd == 0) ? 10 : 12;
  const int K2 = (dd == 0) ? 3 : 4;

  if (dd == 0) {
    for (int i = tid; i < 7290; i += BLK) Us[i] = U3_0[i];
    for (int i = tid; i < 243; i += BLK)  U2s[i] = U2_0[i];
    if (tid < 10) w3l[tid] = w3_0[(e * 10 + tid) * CCH + c];
    else if (tid < 13) w2l[tid - 10] = w2_0[(e * 3 + (tid - 10)) * CCH + c];
    if (tid < 9) R1l[tid] = U1_0[tid] * w1_0[e * CCH + c];
  } else {
    for (int i = tid; i < 8748; i += BLK) Us[i] = U3_1[d * 8748 + i];
    for (int i = tid; i < 324; i += BLK)  U2s[i] = U2_1[d * 324 + i];
    if (tid < 12) w3l[tid] = w3_1[(e * 12 + tid) * CCH + c];
    else if (tid < 16) w2l[tid - 12] = w2_1[(e * 4 + (tid - 12)) * CCH + c];
    if (tid < 9) R1l[tid] = U1_1[d * 9 + tid] * w1_1[e * CCH + c];
  }
  __syncthreads();
  for (int r = tid; r < 729; r += BLK) {
    float acc = 0.f;
    for (int k = 0; k < K3; ++k) acc += Us[r * K3 + k] * w3l[k];
    R3[r] = acc;
  }
  for (int q = tid; q < 81; q += BLK) {
    float acc = 0.f;
    for (int k = 0; k < K2; ++k) acc += U2s[q * K2 + k] * w2l[k];
    R2[q] = acc;
  }
  __syncthreads();
  // pack: Horner consumption order. Per u: [T1s[u], then per v=u..8:
  //   [T2s[u][v], S3s[u][v][w] for w=v..8]].  Per-u size = (10-u)(11-u)/2.
  for (int i = tid; i < TSTR; i += BLK) {
    float val = 0.f;
    if (i < 219) {
      int rem = i, u = 0;
      while (rem >= (10 - u) * (11 - u) / 2) {
        rem -= (10 - u) * (11 - u) / 2; ++u;
      }
      if (rem == 0) {
        val = R1l[u];
      } else {
        rem -= 1;
        int v = u;
        while (rem >= 10 - v) { rem -= 10 - v; ++v; }
        if (rem == 0) {
          val = (u == v) ? R2[u * 9 + v] : R2[u * 9 + v] + R2[v * 9 + u];
        } else {
          int w = v + (rem - 1);
          if (u == v && v == w)
            val = R3[(u * 9 + u) * 9 + u];
          else if (u == v)
            val = R3[(u * 9 + u) * 9 + w] + R3[(u * 9 + w) * 9 + u] +
                  R3[(w * 9 + u) * 9 + u];
          else if (v == w)
            val = R3[(u * 9 + v) * 9 + v] + R3[(v * 9 + u) * 9 + v] +
                  R3[(v * 9 + v) * 9 + u];
          else
            val = R3[(u * 9 + v) * 9 + w] + R3[(u * 9 + w) * 9 + v] +
                  R3[(v * 9 + u) * 9 + w] + R3[(v * 9 + w) * 9 + u] +
                  R3[(w * 9 + u) * 9 + v] + R3[(w * 9 + v) * 9 + u];
        }
      }
    }
    Tg[i] = val;
  }
}

// --- symmetric contraction: triangular Horner over fully-sym table.
//     thread = 1 node x NCPT channels; no LDS; cb via uniform s_load.
__global__ __launch_bounds__(BLK, 6) void contract_kernel(
    const float* __restrict__ feats, const float* __restrict__ table,
    const int* __restrict__ order, const int* __restrict__ offs,
    float* __restrict__ tmp, int NPAD) {
  const int cg = blockIdx.x, e = blockIdx.z;
  const int c0 = cg * NCPT;
  const int start = offs[e], end = offs[e + 1];
  const int pbase = start + blockIdx.y * BLK;
  if (pbase >= end) return;                   // block-uniform early exit
  const int p = pbase + threadIdx.x;
  const bool valid = (p < end);
  const int n = order[valid ? p : (end - 1)]; // clamp: stay in-bounds

  // feats[n][c0..c0+3][0..8]: 36 contiguous floats, 16B-aligned (c0%4==0)
  float tf[NCPT * LDIM];
  {
    const float4* xp =
        (const float4*)(feats + ((size_t)n * CCH + c0) * LDIM);
#pragma unroll
    for (int q = 0; q < 9; ++q) *(float4*)&tf[4 * q] = xp[q];
  }

  const float* Te = table + (size_t)(e * CCH + c0) * TGSTR;

#pragma unroll 1
  for (int dd = 0; dd < 4; ++dd) {
    float accd[NCPT];
#pragma unroll
    for (int c = 0; c < NCPT; ++c) {
      // wave-uniform address (blockIdx/dd/c only) -> s_load (SMEM path)
      const float* B = Te + (size_t)c * TGSTR + dd * TSTR;
      int idx = 0;                            // folds to constants on unroll
      float acc = 0.f;
#pragma unroll
      for (int u = 0; u < 9; ++u) {
        float inner = B[idx++];               // T1s[u]
#pragma unroll
        for (int v = u; v < 9; ++v) {
          float Hv = B[idx++];                // T2sym[u][v]
#pragma unroll
          for (int w = v; w < 9; ++w)
            Hv = fmaf(B[idx++], tf[c * LDIM + w], Hv);
          inner = fmaf(Hv, tf[c * LDIM + v], inner);
        }
        acc = fmaf(inner, tf[c * LDIM + u], acc);
      }
      accd[c] = acc;
    }
    if (valid) {
      float* o = tmp + ((size_t)dd * CCH + c0) * NPAD + p;
#pragma unroll
      for (int c = 0; c < NCPT; ++c) o[(size_t)c * NPAD] = accd[c];
    }
  }
}

// ------------- o3.Linear + residual: LDS-tiled GEMM, coalesced in and out
#define NB 16                 // nodes per block
__global__ __launch_bounds__(BLK, 4) void linear_kernel(
    const float* __restrict__ tmp, const float* __restrict__ W0,
    const float* __restrict__ W1, const float* __restrict__ sc,
    const int* __restrict__ order, float* __restrict__ out, int N, int NPAD) {
  const int p0 = blockIdx.x * NB;
  const int t = threadIdx.x;
  __shared__ __align__(16) float SU[8448];

  // ---- phase 1: stage A[dd][ci][j] = tmp[dd][ci][p0+j], coalesced float4
#pragma unroll
  for (int k = 0; k < 8; ++k) {
    int f = t + k * BLK;               // float4 index 0..2047
    int dd = f >> 9, r = f & 511;
    int ci = r >> 2, q = f & 3;
    float4 v = *(const float4*)(tmp + (size_t)(dd * CCH + ci) * NPAD + p0 + q * 4);
    *(float4*)(SU + dd * 2048 + ci * 16 + q * 4) = v;
  }
  __syncthreads();

  // ---- phase 2: thread = (node j, co-octet o). 32 FMA per ci.
  const int j = t & 15;                // node within tile
  const int o = t >> 4;                // 16 octets of 8 co
  float acc[4][8];
#pragma unroll
  for (int dd = 0; dd < 4; ++dd)
#pragma unroll
    for (int k = 0; k < 8; ++k) acc[dd][k] = 0.f;

  const float* W0p = W0 + o * 8;
  const float* W1p = W1 + o * 8;
#pragma unroll 2
  for (int ci = 0; ci < CCH; ++ci) {
    float a0 = SU[0 * 2048 + ci * 16 + j];
    float a1 = SU[1 * 2048 + ci * 16 + j];
    float a2 = SU[2 * 2048 + ci * 16 + j];
    float a3 = SU[3 * 2048 + ci * 16 + j];
    float4 wa = *(const float4*)(W0p + ci * CCH);
    float4 wb = *(const float4*)(W0p + ci * CCH + 4);
    float4 wc = *(const float4*)(W1p + ci * CCH);
    float4 wd = *(const float4*)(W1p + ci * CCH + 4);
    acc[0][0] = fmaf(a0, wa.x, acc[0][0]);
    acc[0][1] = fmaf(a0, wa.y, acc[0][1]);
    acc[0][2] = fmaf(a0, wa.z, acc[0][2]);
    acc[0][3] = fmaf(a0, wa.w, acc[0][3]);
    acc[0][4] = fmaf(a0, wb.x, acc[0][4]);
    acc[0][5] = fmaf(a0, wb.y, acc[0][5]);
    acc[0][6] = fmaf(a0, wb.z, acc[0][6]);
    acc[0][7] = fmaf(a0, wb.w, acc[0][7]);
    acc[1][0] = fmaf(a1, wc.x, acc[1][0]);
    acc[1][1] = fmaf(a1, wc.y, acc[1][1]);
    acc[1][2] = fmaf(a1, wc.z, acc[1][2]);
    acc[1][3] = fmaf(a1, wc.w, acc[1][3]);
    acc[1][4] = fmaf(a1, wd.x, acc[1][4]);
    acc[1][5] = fmaf(a1, wd.y, acc[1][5]);
    acc[1][6] = fmaf(a1, wd.z, acc[1][6]);
    acc[1][7] = fmaf(a1, wd.w, acc[1][7]);
    acc[2][0] = fmaf(a2, wc.x, acc[2][0]);
    acc[2][1] = fmaf(a2, wc.y, acc[2][1]);
    acc[2][2] = fmaf(a2, wc.z, acc[2][2]);
    acc[2][3] = fmaf(a2, wc.w, acc[2][3]);
    acc[2][4] = fmaf(a2, wd.x, acc[2][4]);
    acc[2][5] = fmaf(a2, wd.y, acc[2][5]);
    acc[2][6] = fmaf(a2, wd.z, acc[2][6]);
    acc[2][7] = fmaf(a2, wd.w, acc[2][7]);
    acc[3][0] = fmaf(a3, wc.x, acc[3][0]);
    acc[3][1] = fmaf(a3, wc.y, acc[3][1]);
    acc[3][2] = fmaf(a3, wc.z, acc[3][2]);
    acc[3][3] = fmaf(a3, wc.w, acc[3][3]);
    acc[3][4] = fmaf(a3, wd.x, acc[3][4]);
    acc[3][5] = fmaf(a3, wd.y, acc[3][5]);
    acc[3][6] = fmaf(a3, wd.z, acc[3][6]);
    acc[3][7] = fmaf(a3, wd.w, acc[3][7]);
  }
  __syncthreads();                     // A dead; SU becomes S[16][516]

  // ---- phase 3: assemble output rows in LDS
  const float s = 0.08838834764831843f;        // 1/sqrt(128)
  float* Sj = SU + j * 516;
#pragma unroll
  for (int k = 0; k < 8; ++k) {
    int co = o * 8 + k;
    Sj[co]               = acc[0][k] * s;
    Sj[CCH + co * 3 + 0] = acc[1][k] * s;
    Sj[CCH + co * 3 + 1] = acc[2][k] * s;
    Sj[CCH + co * 3 + 2] = acc[3][k] * s;
  }
  __syncthreads();

  // ---- phase 4: sc + write, full 512-float rows, float4-coalesced
  const int f = t & 127;               // float4 index within row
  const int jj = t >> 7;
#pragma unroll 1
  for (int jr = jj; jr < NB; jr += 2) {
    int p = p0 + jr;
    if (p < N) {
      int n = order[p];
      float4 sv = ((const float4*)(sc + (size_t)n * 512))[f];
      float4 ov = ((const float4*)(SU + jr * 516))[f];
      ov.x += sv.x; ov.y += sv.y; ov.z += sv.z; ov.w += sv.w;
      ((float4*)(out + (size_t)n * 512))[f] = ov;
    }
  }
}

// -------------------------------------------------------------------- launch
extern "C" void kernel_launch(void* const* d_in, const int* in_sizes, int n_in,
                              void* d_out, int out_size, void* d_ws, size_t ws_size,
                              hipStream_t stream) {
  const float* feats = (const float*)d_in[0];
  const float* attrs = (const float*)d_in[1];
  const float* sc    = (const float*)d_in[2];
  const float* U3_0  = (const float*)d_in[3];
  const float* U2_0  = (const float*)d_in[4];
  const float* U1_0  = (const float*)d_in[5];
  const float* w3_0  = (const float*)d_in[6];
  const float* w2_0  = (const float*)d_in[7];
  const float* w1_0  = (const float*)d_in[8];
  const float* U3_1  = (const float*)d_in[9];
  const float* U2_1  = (const float*)d_in[10];
  const float* U1_1  = (const float*)d_in[11];
  const float* w3_1  = (const float*)d_in[12];
  const float* w2_1  = (const float*)d_in[13];
  const float* w1_1  = (const float*)d_in[14];
  const float* W0    = (const float*)d_in[15];
  const float* W1    = (const float*)d_in[16];

  const int N = in_sizes[0] / (CCH * LDIM);     // 10000
  const int NPAD = ((N + 15) & ~15) + 16;

  // ws (floats): table[5*128*TGSTR] | tmp[4*C][NPAD] | order elem offs(8) cur(8) gcnt(8)
  float* table = (float*)d_ws;
  float* tmp   = table + (size_t)NE * CCH * TGSTR;
  int*   order = (int*)(tmp + (size_t)4 * CCH * NPAD);
  int*   elem  = order + N;
  int*   offs  = elem + N;
  int*   cur   = offs + 8;
  int*   gcnt  = cur + 8;                       // gcnt[0..4], gcnt[5]=done
  float* out   = (float*)d_out;

  hipMemsetAsync(gcnt, 0, 8 * sizeof(int), stream);

  const int nblk = (N + BLK - 1) / BLK;
  count_offs_kernel<<<dim3(nblk), dim3(BLK), 0, stream>>>(
      attrs, N, elem, gcnt, offs, cur);
  scatter_kernel<<<dim3(nblk), dim3(BLK), 0, stream>>>(elem, N, cur, order);

  table_kernel<<<dim3(NE * CCH, 4), dim3(BLK), 0, stream>>>(
      U3_0, U2_0, U1_0, U3_1, U2_1, U1_1,
      w3_0, w2_0, w1_0, w3_1, w2_1, w1_1, table);

  const int chunks = (N + BLK - 1) / BLK;       // worst-case per element
  contract_kernel<<<dim3(CCH / NCPT, chunks, NE), dim3(BLK), 0, stream>>>(
      feats, table, order, offs, tmp, NPAD);

  linear_kernel<<<dim3((N + NB - 1) / NB), dim3(BLK), 0, stream>>>(
      tmp, W0, W1, sc, order, out, N, NPAD);
}

// Round 2
// 281.908 us; speedup vs baseline: 1.0303x; 1.0018x over previous
//
#include <hip/hip_runtime.h>

// EquivariantProductBasisBlock (MACE symmetric contraction, corr=3) + o3.Linear
// N=10000 nodes, C=128 channels, L=9 (lmax=2), E=5 elements, fp32 throughout.
//
// R15 changes vs R14 (linear only; sort/table/contract frozen):
//  - linear_kernel was latency-bound: 625 blocks -> 2.4 blocks/CU, 18%
//    occupancy, VALUBusy 19%, HBM 9% (pure-FMA floor ~8 us, mem floor
//    ~10 us, measured 72 us). NB 16->8: grid 1250, LDS 33->16.5 KB,
//    __launch_bounds__(256,6) -> ~5-6 blocks/CU co-resident.
//  - Thread remap: (8 nodes x 32 co-quads). Per ci: 2 float4 W loads
//    (8 distinct addrs/wave, coalesced+merged) + 4 LDS reads + 16 FMA.
//    ci loop unroll 4 -> ~8 W loads in flight to hide L2 latency.

#define CCH 128
#define LDIM 9
#define NE 5
#define BLK 256
#define NCPT 4               // channels per thread in contraction
#define TSTR 220             // coeffs per (e,c,dd): 219 + 1 pad (16B-aligned)
#define TGSTR 880            // per (e,c) = 4*TSTR
#define U3LDS 8748           // staged U3 slice (729*12 max)

// -------------------------------------------- sort: count + offs (fused)
__global__ __launch_bounds__(BLK) void count_offs_kernel(
    const float* __restrict__ attrs, int N,
    int* __restrict__ elem, int* __restrict__ gcnt,   // gcnt[5], gcnt[5]=done
    int* __restrict__ offs, int* __restrict__ cur) {
  int n = blockIdx.x * BLK + threadIdx.x;
  int e = 0;
  if (n < N) {
    const float* a = attrs + n * NE;
#pragma unroll
    for (int j = 1; j < NE; ++j)
      if (a[j] > 0.5f) e = j;
    elem[n] = e;
  }
  int lane = threadIdx.x & 63;
#pragma unroll
  for (int k = 0; k < NE; ++k) {
    unsigned long long m = __ballot(n < N && e == k);
    if (m) {
      int leader = __ffsll((long long)m) - 1;
      if (lane == leader) atomicAdd(&gcnt[k], __popcll(m));
    }
  }
  __threadfence();
  __syncthreads();
  if (threadIdx.x == 0) {
    int t = atomicAdd(&gcnt[NE], 1);
    if (t == (int)gridDim.x - 1) {            // last block: prefix sum
      int acc = 0;
      for (int k = 0; k < NE; ++k) {
        int ck = atomicAdd(&gcnt[k], 0);      // coherent read
        offs[k] = acc; cur[k] = acc; acc += ck;
      }
      offs[NE] = acc;
    }
  }
}

// ----------------------------------------------------------- sort: scatter
__global__ __launch_bounds__(BLK) void scatter_kernel(
    const int* __restrict__ elem, int N,
    int* __restrict__ cur, int* __restrict__ order) {
  int n = blockIdx.x * BLK + threadIdx.x;
  if (n >= N) return;
  int e = elem[n];
  int lane = threadIdx.x & 63;
#pragma unroll
  for (int k = 0; k < NE; ++k) {
    if (e == k) {
      unsigned long long m = __ballot(1);
      int cnt = __popcll(m);
      int leader = __ffsll((long long)m) - 1;
      int base = 0;
      if (lane == leader) base = atomicAdd(&cur[k], cnt);
      base = __shfl(base, leader);
      int rank = __popcll(m & ((1ull << lane) - 1ull));
      order[base + rank] = n;
    }
  }
}

// ---- build + FULLY (u,v,w)-symmetrize + pack U(x)w tables (one dd/block)
__global__ __launch_bounds__(BLK) void table_kernel(
    const float* __restrict__ U3_0, const float* __restrict__ U2_0,
    const float* __restrict__ U1_0, const float* __restrict__ U3_1,
    const float* __restrict__ U2_1, const float* __restrict__ U1_1,
    const float* __restrict__ w3_0, const float* __restrict__ w2_0,
    const float* __restrict__ w1_0, const float* __restrict__ w3_1,
    const float* __restrict__ w2_1, const float* __restrict__ w1_1,
    float* __restrict__ table) {
  const int b = blockIdx.x;        // e*CCH + c
  const int dd = blockIdx.y;       // 0..3
  const int e = b / CCH, c = b % CCH;
  float* Tg = table + (size_t)b * TGSTR + dd * TSTR;
  __shared__ float Us[U3LDS];      // raw U3 slice [729*K3]
  __shared__ float U2s[324];       // raw U2 slice [81*K2]
  __shared__ float R3[729];        // rect T3
  __shared__ float R2[81];
  __shared__ float R1l[9];
  __shared__ float w3l[12], w2l[4];
  const int tid = threadIdx.x;
  const int d = dd - 1;
  const int K3 = (dd == 0) ? 10 : 12;
  const int K2 = (dd == 0) ? 3 : 4;

  if (dd == 0) {
    for (int i = tid; i < 7290; i += BLK) Us[i] = U3_0[i];
    for (int i = tid; i < 243; i += BLK)  U2s[i] = U2_0[i];
    if (tid < 10) w3l[tid] = w3_0[(e * 10 + tid) * CCH + c];
    else if (tid < 13) w2l[tid - 10] = w2_0[(e * 3 + (tid - 10)) * CCH + c];
    if (tid < 9) R1l[tid] = U1_0[tid] * w1_0[e * CCH + c];
  } else {
    for (int i = tid; i < 8748; i += BLK) Us[i] = U3_1[d * 8748 + i];
    for (int i = tid; i < 324; i += BLK)  U2s[i] = U2_1[d * 324 + i];
    if (tid < 12) w3l[tid] = w3_1[(e * 12 + tid) * CCH + c];
    else if (tid < 16) w2l[tid - 12] = w2_1[(e * 4 + (tid - 12)) * CCH + c];
    if (tid < 9) R1l[tid] = U1_1[d * 9 + tid] * w1_1[e * CCH + c];
  }
  __syncthreads();
  for (int r = tid; r < 729; r += BLK) {
    float acc = 0.f;
    for (int k = 0; k < K3; ++k) acc += Us[r * K3 + k] * w3l[k];
    R3[r] = acc;
  }
  for (int q = tid; q < 81; q += BLK) {
    float acc = 0.f;
    for (int k = 0; k < K2; ++k) acc += U2s[q * K2 + k] * w2l[k];
    R2[q] = acc;
  }
  __syncthreads();
  // pack: Horner consumption order. Per u: [T1s[u], then per v=u..8:
  //   [T2s[u][v], S3s[u][v][w] for w=v..8]].  Per-u size = (10-u)(11-u)/2.
  for (int i = tid; i < TSTR; i += BLK) {
    float val = 0.f;
    if (i < 219) {
      int rem = i, u = 0;
      while (rem >= (10 - u) * (11 - u) / 2) {
        rem -= (10 - u) * (11 - u) / 2; ++u;
      }
      if (rem == 0) {
        val = R1l[u];
      } else {
        rem -= 1;
        int v = u;
        while (rem >= 10 - v) { rem -= 10 - v; ++v; }
        if (rem == 0) {
          val = (u == v) ? R2[u * 9 + v] : R2[u * 9 + v] + R2[v * 9 + u];
        } else {
          int w = v + (rem - 1);
          if (u == v && v == w)
            val = R3[(u * 9 + u) * 9 + u];
          else if (u == v)
            val = R3[(u * 9 + u) * 9 + w] + R3[(u * 9 + w) * 9 + u] +
                  R3[(w * 9 + u) * 9 + u];
          else if (v == w)
            val = R3[(u * 9 + v) * 9 + v] + R3[(v * 9 + u) * 9 + v] +
                  R3[(v * 9 + v) * 9 + u];
          else
            val = R3[(u * 9 + v) * 9 + w] + R3[(u * 9 + w) * 9 + v] +
                  R3[(v * 9 + u) * 9 + w] + R3[(v * 9 + w) * 9 + u] +
                  R3[(w * 9 + u) * 9 + v] + R3[(w * 9 + v) * 9 + u];
        }
      }
    }
    Tg[i] = val;
  }
}

// --- symmetric contraction: triangular Horner over fully-sym table.
//     thread = 1 node x NCPT channels; no LDS; cb via uniform s_load.
__global__ __launch_bounds__(BLK, 6) void contract_kernel(
    const float* __restrict__ feats, const float* __restrict__ table,
    const int* __restrict__ order, const int* __restrict__ offs,
    float* __restrict__ tmp, int NPAD) {
  const int cg = blockIdx.x, e = blockIdx.z;
  const int c0 = cg * NCPT;
  const int start = offs[e], end = offs[e + 1];
  const int pbase = start + blockIdx.y * BLK;
  if (pbase >= end) return;                   // block-uniform early exit
  const int p = pbase + threadIdx.x;
  const bool valid = (p < end);
  const int n = order[valid ? p : (end - 1)]; // clamp: stay in-bounds

  // feats[n][c0..c0+3][0..8]: 36 contiguous floats, 16B-aligned (c0%4==0)
  float tf[NCPT * LDIM];
  {
    const float4* xp =
        (const float4*)(feats + ((size_t)n * CCH + c0) * LDIM);
#pragma unroll
    for (int q = 0; q < 9; ++q) *(float4*)&tf[4 * q] = xp[q];
  }

  const float* Te = table + (size_t)(e * CCH + c0) * TGSTR;

#pragma unroll 1
  for (int dd = 0; dd < 4; ++dd) {
    float accd[NCPT];
#pragma unroll
    for (int c = 0; c < NCPT; ++c) {
      // wave-uniform address (blockIdx/dd/c only) -> s_load (SMEM path)
      const float* B = Te + (size_t)c * TGSTR + dd * TSTR;
      int idx = 0;                            // folds to constants on unroll
      float acc = 0.f;
#pragma unroll
      for (int u = 0; u < 9; ++u) {
        float inner = B[idx++];               // T1s[u]
#pragma unroll
        for (int v = u; v < 9; ++v) {
          float Hv = B[idx++];                // T2sym[u][v]
#pragma unroll
          for (int w = v; w < 9; ++w)
            Hv = fmaf(B[idx++], tf[c * LDIM + w], Hv);
          inner = fmaf(Hv, tf[c * LDIM + v], inner);
        }
        acc = fmaf(inner, tf[c * LDIM + u], acc);
      }
      accd[c] = acc;
    }
    if (valid) {
      float* o = tmp + ((size_t)dd * CCH + c0) * NPAD + p;
#pragma unroll
      for (int c = 0; c < NCPT; ++c) o[(size_t)c * NPAD] = accd[c];
    }
  }
}

// ------------- o3.Linear + residual: LDS-tiled GEMM, coalesced in and out
#define NB 8                  // nodes per block (R15: 16->8 for occupancy)
__global__ __launch_bounds__(BLK, 6) void linear_kernel(
    const float* __restrict__ tmp, const float* __restrict__ W0,
    const float* __restrict__ W1, const float* __restrict__ sc,
    const int* __restrict__ order, float* __restrict__ out, int N, int NPAD) {
  const int p0 = blockIdx.x * NB;
  const int t = threadIdx.x;
  __shared__ __align__(16) float SU[4128];   // max(4*128*8, 8*516) floats

  // ---- phase 1: stage A[dd][ci][j] = tmp[dd][ci][p0+j], coalesced float4
  // 1024 float4 total: f = t + k*BLK; dd = f>>8, ci = (f&255)>>1, q = f&1
#pragma unroll
  for (int k = 0; k < 4; ++k) {
    int f = t + k * BLK;
    int dd = f >> 8, r = f & 255;
    int ci = r >> 1, q = r & 1;
    float4 v = *(const float4*)(tmp + (size_t)(dd * CCH + ci) * NPAD + p0 + q * 4);
    *(float4*)(SU + dd * 1024 + ci * 8 + q * 4) = v;
  }
  __syncthreads();

  // ---- phase 2: thread = (node j 0..7, co-quad o 0..31). 16 FMA per ci.
  const int j = t & 7;
  const int o = t >> 3;
  float acc[4][4];
#pragma unroll
  for (int dd = 0; dd < 4; ++dd)
#pragma unroll
    for (int k = 0; k < 4; ++k) acc[dd][k] = 0.f;

  const float* W0p = W0 + o * 4;
  const float* W1p = W1 + o * 4;
#pragma unroll 4
  for (int ci = 0; ci < CCH; ++ci) {
    float a0 = SU[0 * 1024 + ci * 8 + j];
    float a1 = SU[1 * 1024 + ci * 8 + j];
    float a2 = SU[2 * 1024 + ci * 8 + j];
    float a3 = SU[3 * 1024 + ci * 8 + j];
    float4 wa = *(const float4*)(W0p + ci * CCH);
    float4 wc = *(const float4*)(W1p + ci * CCH);
    acc[0][0] = fmaf(a0, wa.x, acc[0][0]);
    acc[0][1] = fmaf(a0, wa.y, acc[0][1]);
    acc[0][2] = fmaf(a0, wa.z, acc[0][2]);
    acc[0][3] = fmaf(a0, wa.w, acc[0][3]);
    acc[1][0] = fmaf(a1, wc.x, acc[1][0]);
    acc[1][1] = fmaf(a1, wc.y, acc[1][1]);
    acc[1][2] = fmaf(a1, wc.z, acc[1][2]);
    acc[1][3] = fmaf(a1, wc.w, acc[1][3]);
    acc[2][0] = fmaf(a2, wc.x, acc[2][0]);
    acc[2][1] = fmaf(a2, wc.y, acc[2][1]);
    acc[2][2] = fmaf(a2, wc.z, acc[2][2]);
    acc[2][3] = fmaf(a2, wc.w, acc[2][3]);
    acc[3][0] = fmaf(a3, wc.x, acc[3][0]);
    acc[3][1] = fmaf(a3, wc.y, acc[3][1]);
    acc[3][2] = fmaf(a3, wc.z, acc[3][2]);
    acc[3][3] = fmaf(a3, wc.w, acc[3][3]);
  }
  __syncthreads();                     // A dead; SU becomes S[8][516]

  // ---- phase 3: assemble output rows in LDS
  const float s = 0.08838834764831843f;        // 1/sqrt(128)
  float* Sj = SU + j * 516;
#pragma unroll
  for (int k = 0; k < 4; ++k) {
    int co = o * 4 + k;
    Sj[co]               = acc[0][k] * s;
    Sj[CCH + co * 3 + 0] = acc[1][k] * s;
    Sj[CCH + co * 3 + 1] = acc[2][k] * s;
    Sj[CCH + co * 3 + 2] = acc[3][k] * s;
  }
  __syncthreads();

  // ---- phase 4: sc + write, full 512-float rows, float4-coalesced
  const int f = t & 127;               // float4 index within row
  const int jj = t >> 7;
#pragma unroll 1
  for (int jr = jj; jr < NB; jr += 2) {
    int p = p0 + jr;
    if (p < N) {
      int n = order[p];
      float4 sv = ((const float4*)(sc + (size_t)n * 512))[f];
      float4 ov = ((const float4*)(SU + jr * 516))[f];
      ov.x += sv.x; ov.y += sv.y; ov.z += sv.z; ov.w += sv.w;
      ((float4*)(out + (size_t)n * 512))[f] = ov;
    }
  }
}

// -------------------------------------------------------------------- launch
extern "C" void kernel_launch(void* const* d_in, const int* in_sizes, int n_in,
                              void* d_out, int out_size, void* d_ws, size_t ws_size,
                              hipStream_t stream) {
  const float* feats = (const float*)d_in[0];
  const float* attrs = (const float*)d_in[1];
  const float* sc    = (const float*)d_in[2];
  const float* U3_0  = (const float*)d_in[3];
  const float* U2_0  = (const float*)d_in[4];
  const float* U1_0  = (const float*)d_in[5];
  const float* w3_0  = (const float*)d_in[6];
  const float* w2_0  = (const float*)d_in[7];
  const float* w1_0  = (const float*)d_in[8];
  const float* U3_1  = (const float*)d_in[9];
  const float* U2_1  = (const float*)d_in[10];
  const float* U1_1  = (const float*)d_in[11];
  const float* w3_1  = (const float*)d_in[12];
  const float* w2_1  = (const float*)d_in[13];
  const float* w1_1  = (const float*)d_in[14];
  const float* W0    = (const float*)d_in[15];
  const float* W1    = (const float*)d_in[16];

  const int N = in_sizes[0] / (CCH * LDIM);     // 10000
  const int NPAD = ((N + 15) & ~15) + 16;

  // ws (floats): table[5*128*TGSTR] | tmp[4*C][NPAD] | order elem offs(8) cur(8) gcnt(8)
  float* table = (float*)d_ws;
  float* tmp   = table + (size_t)NE * CCH * TGSTR;
  int*   order = (int*)(tmp + (size_t)4 * CCH * NPAD);
  int*   elem  = order + N;
  int*   offs  = elem + N;
  int*   cur   = offs + 8;
  int*   gcnt  = cur + 8;                       // gcnt[0..4], gcnt[5]=done
  float* out   = (float*)d_out;

  hipMemsetAsync(gcnt, 0, 8 * sizeof(int), stream);

  const int nblk = (N + BLK - 1) / BLK;
  count_offs_kernel<<<dim3(nblk), dim3(BLK), 0, stream>>>(
      attrs, N, elem, gcnt, offs, cur);
  scatter_kernel<<<dim3(nblk), dim3(BLK), 0, stream>>>(elem, N, cur, order);

  table_kernel<<<dim3(NE * CCH, 4), dim3(BLK), 0, stream>>>(
      U3_0, U2_0, U1_0, U3_1, U2_1, U1_1,
      w3_0, w2_0, w1_0, w3_1, w2_1, w1_1, table);

  const int chunks = (N + BLK - 1) / BLK;       // worst-case per element
  contract_kernel<<<dim3(CCH / NCPT, chunks, NE), dim3(BLK), 0, stream>>>(
      feats, table, order, offs, tmp, NPAD);

  linear_kernel<<<dim3((N + NB - 1) / NB), dim3(BLK), 0, stream>>>(
      tmp, W0, W1, sc, order, out, N, NPAD);
}

// Round 3
// 266.391 us; speedup vs baseline: 1.0903x; 1.0583x over previous
//
#include <hip/hip_runtime.h>

// EquivariantProductBasisBlock (MACE symmetric contraction, corr=3) + o3.Linear
// N=10000 nodes, C=128 channels, L=9 (lmax=2), E=5 elements, fp32 throughout.
//
// R16 changes vs R15:
//  - contract: NCPT 4->1 (thread = 1 node x 1 channel). Waves 5000->20000
//    (occupancy cap was 61% structural; now 2.5x oversubscribed). Fully
//    unrolled Horner shrinks to ~900 FMA ~8KB -> fits 32KB L1I (NCPT=4 was
//    ~30KB+, thrashing). s_load coeff stream per wave quarters. Compact
//    grid: blockIdx.y = global chunk, mapped to (e,segment) in-kernel from
//    offs -> no empty-block dispatch (was 6400 blocks, ~1400 real).
//    __launch_bounds__(256,8).
//  - linear: R15 showed VGPR=32 -> compiler held ~2 W loads in flight ->
//    exposed L2 latency every ci despite 41% occupancy. Explicit rolling
//    prefetch (distance 1, unroll 2, 8 float4 in flight) + launch_bounds
//    (256,5) to raise the VGPR cap (~96). Same math order.

#define CCH 128
#define LDIM 9
#define NE 5
#define BLK 256
#define TSTR 220             // coeffs per (e,c,dd): 219 + 1 pad (16B-aligned)
#define TGSTR 880            // per (e,c) = 4*TSTR
#define U3LDS 8748           // staged U3 slice (729*12 max)

// -------------------------------------------- sort: count + offs (fused)
__global__ __launch_bounds__(BLK) void count_offs_kernel(
    const float* __restrict__ attrs, int N,
    int* __restrict__ elem, int* __restrict__ gcnt,   // gcnt[5], gcnt[5]=done
    int* __restrict__ offs, int* __restrict__ cur) {
  int n = blockIdx.x * BLK + threadIdx.x;
  int e = 0;
  if (n < N) {
    const float* a = attrs + n * NE;
#pragma unroll
    for (int j = 1; j < NE; ++j)
      if (a[j] > 0.5f) e = j;
    elem[n] = e;
  }
  int lane = threadIdx.x & 63;
#pragma unroll
  for (int k = 0; k < NE; ++k) {
    unsigned long long m = __ballot(n < N && e == k);
    if (m) {
      int leader = __ffsll((long long)m) - 1;
      if (lane == leader) atomicAdd(&gcnt[k], __popcll(m));
    }
  }
  __threadfence();
  __syncthreads();
  if (threadIdx.x == 0) {
    int t = atomicAdd(&gcnt[NE], 1);
    if (t == (int)gridDim.x - 1) {            // last block: prefix sum
      int acc = 0;
      for (int k = 0; k < NE; ++k) {
        int ck = atomicAdd(&gcnt[k], 0);      // coherent read
        offs[k] = acc; cur[k] = acc; acc += ck;
      }
      offs[NE] = acc;
    }
  }
}

// ----------------------------------------------------------- sort: scatter
__global__ __launch_bounds__(BLK) void scatter_kernel(
    const int* __restrict__ elem, int N,
    int* __restrict__ cur, int* __restrict__ order) {
  int n = blockIdx.x * BLK + threadIdx.x;
  if (n >= N) return;
  int e = elem[n];
  int lane = threadIdx.x & 63;
#pragma unroll
  for (int k = 0; k < NE; ++k) {
    if (e == k) {
      unsigned long long m = __ballot(1);
      int cnt = __popcll(m);
      int leader = __ffsll((long long)m) - 1;
      int base = 0;
      if (lane == leader) base = atomicAdd(&cur[k], cnt);
      base = __shfl(base, leader);
      int rank = __popcll(m & ((1ull << lane) - 1ull));
      order[base + rank] = n;
    }
  }
}

// ---- build + FULLY (u,v,w)-symmetrize + pack U(x)w tables (one dd/block)
__global__ __launch_bounds__(BLK) void table_kernel(
    const float* __restrict__ U3_0, const float* __restrict__ U2_0,
    const float* __restrict__ U1_0, const float* __restrict__ U3_1,
    const float* __restrict__ U2_1, const float* __restrict__ U1_1,
    const float* __restrict__ w3_0, const float* __restrict__ w2_0,
    const float* __restrict__ w1_0, const float* __restrict__ w3_1,
    const float* __restrict__ w2_1, const float* __restrict__ w1_1,
    float* __restrict__ table) {
  const int b = blockIdx.x;        // e*CCH + c
  const int dd = blockIdx.y;       // 0..3
  const int e = b / CCH, c = b % CCH;
  float* Tg = table + (size_t)b * TGSTR + dd * TSTR;
  __shared__ float Us[U3LDS];      // raw U3 slice [729*K3]
  __shared__ float U2s[324];       // raw U2 slice [81*K2]
  __shared__ float R3[729];        // rect T3
  __shared__ float R2[81];
  __shared__ float R1l[9];
  __shared__ float w3l[12], w2l[4];
  const int tid = threadIdx.x;
  const int d = dd - 1;
  const int K3 = (dd == 0) ? 10 : 12;
  const int K2 = (dd == 0) ? 3 : 4;

  if (dd == 0) {
    for (int i = tid; i < 7290; i += BLK) Us[i] = U3_0[i];
    for (int i = tid; i < 243; i += BLK)  U2s[i] = U2_0[i];
    if (tid < 10) w3l[tid] = w3_0[(e * 10 + tid) * CCH + c];
    else if (tid < 13) w2l[tid - 10] = w2_0[(e * 3 + (tid - 10)) * CCH + c];
    if (tid < 9) R1l[tid] = U1_0[tid] * w1_0[e * CCH + c];
  } else {
    for (int i = tid; i < 8748; i += BLK) Us[i] = U3_1[d * 8748 + i];
    for (int i = tid; i < 324; i += BLK)  U2s[i] = U2_1[d * 324 + i];
    if (tid < 12) w3l[tid] = w3_1[(e * 12 + tid) * CCH + c];
    else if (tid < 16) w2l[tid - 12] = w2_1[(e * 4 + (tid - 12)) * CCH + c];
    if (tid < 9) R1l[tid] = U1_1[d * 9 + tid] * w1_1[e * CCH + c];
  }
  __syncthreads();
  for (int r = tid; r < 729; r += BLK) {
    float acc = 0.f;
    for (int k = 0; k < K3; ++k) acc += Us[r * K3 + k] * w3l[k];
    R3[r] = acc;
  }
  for (int q = tid; q < 81; q += BLK) {
    float acc = 0.f;
    for (int k = 0; k < K2; ++k) acc += U2s[q * K2 + k] * w2l[k];
    R2[q] = acc;
  }
  __syncthreads();
  // pack: Horner consumption order. Per u: [T1s[u], then per v=u..8:
  //   [T2s[u][v], S3s[u][v][w] for w=v..8]].  Per-u size = (10-u)(11-u)/2.
  for (int i = tid; i < TSTR; i += BLK) {
    float val = 0.f;
    if (i < 219) {
      int rem = i, u = 0;
      while (rem >= (10 - u) * (11 - u) / 2) {
        rem -= (10 - u) * (11 - u) / 2; ++u;
      }
      if (rem == 0) {
        val = R1l[u];
      } else {
        rem -= 1;
        int v = u;
        while (rem >= 10 - v) { rem -= 10 - v; ++v; }
        if (rem == 0) {
          val = (u == v) ? R2[u * 9 + v] : R2[u * 9 + v] + R2[v * 9 + u];
        } else {
          int w = v + (rem - 1);
          if (u == v && v == w)
            val = R3[(u * 9 + u) * 9 + u];
          else if (u == v)
            val = R3[(u * 9 + u) * 9 + w] + R3[(u * 9 + w) * 9 + u] +
                  R3[(w * 9 + u) * 9 + u];
          else if (v == w)
            val = R3[(u * 9 + v) * 9 + v] + R3[(v * 9 + u) * 9 + v] +
                  R3[(v * 9 + v) * 9 + u];
          else
            val = R3[(u * 9 + v) * 9 + w] + R3[(u * 9 + w) * 9 + v] +
                  R3[(v * 9 + u) * 9 + w] + R3[(v * 9 + w) * 9 + u] +
                  R3[(w * 9 + u) * 9 + v] + R3[(w * 9 + v) * 9 + u];
        }
      }
    }
    Tg[i] = val;
  }
}

// --- symmetric contraction: triangular Horner over fully-sym table.
//     thread = 1 node x 1 channel; no LDS; cb via uniform s_load.
//     blockIdx.y = global chunk -> (e, segment) via offs (compact grid).
__global__ __launch_bounds__(BLK, 8) void contract_kernel(
    const float* __restrict__ feats, const float* __restrict__ table,
    const int* __restrict__ order, const int* __restrict__ offs,
    float* __restrict__ tmp, int NPAD) {
  const int c = blockIdx.x;                   // 0..127
  // map global chunk -> (element e, node range) ; wave-uniform
  int rem = blockIdx.y;
  int e = -1, pbase = 0, segend = 0;
#pragma unroll
  for (int k = 0; k < NE; ++k) {
    int st = offs[k], en = offs[k + 1];
    int nc = (en - st + BLK - 1) >> 8;        // chunks in segment k (BLK=256)
    if (e < 0) {
      if (rem < nc) { e = k; pbase = st + rem * BLK; segend = en; }
      else rem -= nc;
    }
  }
  if (e < 0) return;                          // slack chunk

  const int p = pbase + threadIdx.x;
  const bool valid = (p < segend);
  const int n = order[valid ? p : (segend - 1)];  // clamp: stay in-bounds

  float tf[LDIM];
  {
    const float* xp = feats + ((size_t)n * CCH + c) * LDIM;
#pragma unroll
    for (int q = 0; q < LDIM; ++q) tf[q] = xp[q];
  }

  const float* Tc = table + (size_t)(e * CCH + c) * TGSTR;

#pragma unroll 1
  for (int dd = 0; dd < 4; ++dd) {
    // wave-uniform address (blockIdx/dd only) -> s_load (SMEM path)
    const float* B = Tc + dd * TSTR;
    int idx = 0;                              // folds to constants on unroll
    float acc = 0.f;
#pragma unroll
    for (int u = 0; u < 9; ++u) {
      float inner = B[idx++];                 // T1s[u]
#pragma unroll
      for (int v = u; v < 9; ++v) {
        float Hv = B[idx++];                  // T2sym[u][v]
#pragma unroll
        for (int w = v; w < 9; ++w)
          Hv = fmaf(B[idx++], tf[w], Hv);
        inner = fmaf(Hv, tf[v], inner);
      }
      acc = fmaf(inner, tf[u], acc);
    }
    if (valid) tmp[((size_t)dd * CCH + c) * NPAD + p] = acc;
  }
}

// ------------- o3.Linear + residual: LDS-tiled GEMM, coalesced in and out
#define NB 8                  // nodes per block
__global__ __launch_bounds__(BLK, 5) void linear_kernel(
    const float* __restrict__ tmp, const float* __restrict__ W0,
    const float* __restrict__ W1, const float* __restrict__ sc,
    const int* __restrict__ order, float* __restrict__ out, int N, int NPAD) {
  const int p0 = blockIdx.x * NB;
  const int t = threadIdx.x;
  __shared__ __align__(16) float SU[4128];   // max(4*128*8, 8*516) floats

  // ---- phase 1: stage A[dd][ci][j] = tmp[dd][ci][p0+j], coalesced float4
#pragma unroll
  for (int k = 0; k < 4; ++k) {
    int f = t + k * BLK;
    int dd = f >> 8, r = f & 255;
    int ci = r >> 1, q = r & 1;
    float4 v = *(const float4*)(tmp + (size_t)(dd * CCH + ci) * NPAD + p0 + q * 4);
    *(float4*)(SU + dd * 1024 + ci * 8 + q * 4) = v;
  }
  __syncthreads();

  // ---- phase 2: thread = (node j 0..7, co-quad o 0..31). 16 FMA per ci.
  //      explicit rolling W prefetch: distance 1 (2 ci), 8 float4 in flight.
  const int j = t & 7;
  const int o = t >> 3;
  float acc[4][4];
#pragma unroll
  for (int dd = 0; dd < 4; ++dd)
#pragma unroll
    for (int k = 0; k < 4; ++k) acc[dd][k] = 0.f;

  const float* W0p = W0 + o * 4;
  const float* W1p = W1 + o * 4;
  float4 wa0 = *(const float4*)(W0p + 0 * CCH);
  float4 wc0 = *(const float4*)(W1p + 0 * CCH);
  float4 wa1 = *(const float4*)(W0p + 1 * CCH);
  float4 wc1 = *(const float4*)(W1p + 1 * CCH);
#pragma unroll 2
  for (int ci = 0; ci < CCH; ci += 2) {
    const int cn = (ci + 2) & 127;           // wraps at end: harmless reload
    float4 pa0 = *(const float4*)(W0p + cn * CCH);
    float4 pc0 = *(const float4*)(W1p + cn * CCH);
    float4 pa1 = *(const float4*)(W0p + (cn + 1) * CCH);
    float4 pc1 = *(const float4*)(W1p + (cn + 1) * CCH);

    float a0 = SU[0 * 1024 + ci * 8 + j];
    float a1 = SU[1 * 1024 + ci * 8 + j];
    float a2 = SU[2 * 1024 + ci * 8 + j];
    float a3 = SU[3 * 1024 + ci * 8 + j];
    acc[0][0] = fmaf(a0, wa0.x, acc[0][0]);
    acc[0][1] = fmaf(a0, wa0.y, acc[0][1]);
    acc[0][2] = fmaf(a0, wa0.z, acc[0][2]);
    acc[0][3] = fmaf(a0, wa0.w, acc[0][3]);
    acc[1][0] = fmaf(a1, wc0.x, acc[1][0]);
    acc[1][1] = fmaf(a1, wc0.y, acc[1][1]);
    acc[1][2] = fmaf(a1, wc0.z, acc[1][2]);
    acc[1][3] = fmaf(a1, wc0.w, acc[1][3]);
    acc[2][0] = fmaf(a2, wc0.x, acc[2][0]);
    acc[2][1] = fmaf(a2, wc0.y, acc[2][1]);
    acc[2][2] = fmaf(a2, wc0.z, acc[2][2]);
    acc[2][3] = fmaf(a2, wc0.w, acc[2][3]);
    acc[3][0] = fmaf(a3, wc0.x, acc[3][0]);
    acc[3][1] = fmaf(a3, wc0.y, acc[3][1]);
    acc[3][2] = fmaf(a3, wc0.z, acc[3][2]);
    acc[3][3] = fmaf(a3, wc0.w, acc[3][3]);

    float b0 = SU[0 * 1024 + (ci + 1) * 8 + j];
    float b1 = SU[1 * 1024 + (ci + 1) * 8 + j];
    float b2 = SU[2 * 1024 + (ci + 1) * 8 + j];
    float b3 = SU[3 * 1024 + (ci + 1) * 8 + j];
    acc[0][0] = fmaf(b0, wa1.x, acc[0][0]);
    acc[0][1] = fmaf(b0, wa1.y, acc[0][1]);
    acc[0][2] = fmaf(b0, wa1.z, acc[0][2]);
    acc[0][3] = fmaf(b0, wa1.w, acc[0][3]);
    acc[1][0] = fmaf(b1, wc1.x, acc[1][0]);
    acc[1][1] = fmaf(b1, wc1.y, acc[1][1]);
    acc[1][2] = fmaf(b1, wc1.z, acc[1][2]);
    acc[1][3] = fmaf(b1, wc1.w, acc[1][3]);
    acc[2][0] = fmaf(b2, wc1.x, acc[2][0]);
    acc[2][1] = fmaf(b2, wc1.y, acc[2][1]);
    acc[2][2] = fmaf(b2, wc1.z, acc[2][2]);
    acc[2][3] = fmaf(b2, wc1.w, acc[2][3]);
    acc[3][0] = fmaf(b3, wc1.x, acc[3][0]);
    acc[3][1] = fmaf(b3, wc1.y, acc[3][1]);
    acc[3][2] = fmaf(b3, wc1.z, acc[3][2]);
    acc[3][3] = fmaf(b3, wc1.w, acc[3][3]);

    wa0 = pa0; wc0 = pc0; wa1 = pa1; wc1 = pc1;
  }
  __syncthreads();                     // A dead; SU becomes S[8][516]

  // ---- phase 3: assemble output rows in LDS
  const float s = 0.08838834764831843f;        // 1/sqrt(128)
  float* Sj = SU + j * 516;
#pragma unroll
  for (int k = 0; k < 4; ++k) {
    int co = o * 4 + k;
    Sj[co]               = acc[0][k] * s;
    Sj[CCH + co * 3 + 0] = acc[1][k] * s;
    Sj[CCH + co * 3 + 1] = acc[2][k] * s;
    Sj[CCH + co * 3 + 2] = acc[3][k] * s;
  }
  __syncthreads();

  // ---- phase 4: sc + write, full 512-float rows, float4-coalesced
  const int f = t & 127;               // float4 index within row
  const int jj = t >> 7;
#pragma unroll 1
  for (int jr = jj; jr < NB; jr += 2) {
    int p = p0 + jr;
    if (p < N) {
      int n = order[p];
      float4 sv = ((const float4*)(sc + (size_t)n * 512))[f];
      float4 ov = ((const float4*)(SU + jr * 516))[f];
      ov.x += sv.x; ov.y += sv.y; ov.z += sv.z; ov.w += sv.w;
      ((float4*)(out + (size_t)n * 512))[f] = ov;
    }
  }
}

// -------------------------------------------------------------------- launch
extern "C" void kernel_launch(void* const* d_in, const int* in_sizes, int n_in,
                              void* d_out, int out_size, void* d_ws, size_t ws_size,
                              hipStream_t stream) {
  const float* feats = (const float*)d_in[0];
  const float* attrs = (const float*)d_in[1];
  const float* sc    = (const float*)d_in[2];
  const float* U3_0  = (const float*)d_in[3];
  const float* U2_0  = (const float*)d_in[4];
  const float* U1_0  = (const float*)d_in[5];
  const float* w3_0  = (const float*)d_in[6];
  const float* w2_0  = (const float*)d_in[7];
  const float* w1_0  = (const float*)d_in[8];
  const float* U3_1  = (const float*)d_in[9];
  const float* U2_1  = (const float*)d_in[10];
  const float* U1_1  = (const float*)d_in[11];
  const float* w3_1  = (const float*)d_in[12];
  const float* w2_1  = (const float*)d_in[13];
  const float* w1_1  = (const float*)d_in[14];
  const float* W0    = (const float*)d_in[15];
  const float* W1    = (const float*)d_in[16];

  const int N = in_sizes[0] / (CCH * LDIM);     // 10000
  const int NPAD = ((N + 15) & ~15) + 16;

  // ws (floats): table[5*128*TGSTR] | tmp[4*C][NPAD] | order elem offs(8) cur(8) gcnt(8)
  float* table = (float*)d_ws;
  float* tmp   = table + (size_t)NE * CCH * TGSTR;
  int*   order = (int*)(tmp + (size_t)4 * CCH * NPAD);
  int*   elem  = order + N;
  int*   offs  = elem + N;
  int*   cur   = offs + 8;
  int*   gcnt  = cur + 8;                       // gcnt[0..4], gcnt[5]=done
  float* out   = (float*)d_out;

  hipMemsetAsync(gcnt, 0, 8 * sizeof(int), stream);

  const int nblk = (N + BLK - 1) / BLK;
  count_offs_kernel<<<dim3(nblk), dim3(BLK), 0, stream>>>(
      attrs, N, elem, gcnt, offs, cur);
  scatter_kernel<<<dim3(nblk), dim3(BLK), 0, stream>>>(elem, N, cur, order);

  table_kernel<<<dim3(NE * CCH, 4), dim3(BLK), 0, stream>>>(
      U3_0, U2_0, U1_0, U3_1, U2_1, U1_1,
      w3_0, w2_0, w1_0, w3_1, w2_1, w1_1, table);

  // compact chunk grid: sum over e of ceil(cnt_e/BLK) <= N/BLK + NE
  const int chunksMax = (N + BLK - 1) / BLK + NE;
  contract_kernel<<<dim3(CCH, chunksMax), dim3(BLK), 0, stream>>>(
      feats, table, order, offs, tmp, NPAD);

  linear_kernel<<<dim3((N + NB - 1) / NB), dim3(BLK), 0, stream>>>(
      tmp, W0, W1, sc, order, out, N, NPAD);
}

// Round 4
// 259.459 us; speedup vs baseline: 1.1194x; 1.0267x over previous
//
#include <hip/hip_runtime.h>

// EquivariantProductBasisBlock (MACE symmetric contraction, corr=3) + o3.Linear
// N=10000 nodes, C=128 channels, L=9 (lmax=2), E=5 elements, fp32 throughout.
//
// R17 changes vs R16 (linear only; sort/table/contract frozen):
//  - R16 evidence: linear VGPR stayed 32 -> hipcc de-pipelined the rolling
//    W prefetch (sinks loads to use site, minimizes VGPRs). Phase 2 was an
//    exposed ~250cy L2 latency per ci-pair (VALUBusy 25% == work/(work+stall)).
//  - Fix: compiler-proof pipelining via LDS double-buffer + global_load_lds
//    (direct-to-LDS DMA, no VGPR round-trip, nothing to de-pipeline).
//    W staged in 8 chunks of 16 ci (2 x 16 KB dbuf); chunk k+1 issued before
//    computing chunk k; HIP's mandatory vmcnt(0) drain at __syncthreads
//    guarantees chunk completeness; ~1400cy FMA/chunk covers ~300cy latency.
//  - NB=16, thread = (j2, o) owns 2 nodes x 4 co x 4 dd = 32 FMA/ci (2x
//    arithmetic intensity vs R16). LDS 64 KB -> 2 blocks/CU: ILP over TLP.

#define CCH 128
#define LDIM 9
#define NE 5
#define BLK 256
#define TSTR 220             // coeffs per (e,c,dd): 219 + 1 pad (16B-aligned)
#define TGSTR 880            // per (e,c) = 4*TSTR
#define U3LDS 8748           // staged U3 slice (729*12 max)

// -------------------------------------------- sort: count + offs (fused)
__global__ __launch_bounds__(BLK) void count_offs_kernel(
    const float* __restrict__ attrs, int N,
    int* __restrict__ elem, int* __restrict__ gcnt,   // gcnt[5], gcnt[5]=done
    int* __restrict__ offs, int* __restrict__ cur) {
  int n = blockIdx.x * BLK + threadIdx.x;
  int e = 0;
  if (n < N) {
    const float* a = attrs + n * NE;
#pragma unroll
    for (int j = 1; j < NE; ++j)
      if (a[j] > 0.5f) e = j;
    elem[n] = e;
  }
  int lane = threadIdx.x & 63;
#pragma unroll
  for (int k = 0; k < NE; ++k) {
    unsigned long long m = __ballot(n < N && e == k);
    if (m) {
      int leader = __ffsll((long long)m) - 1;
      if (lane == leader) atomicAdd(&gcnt[k], __popcll(m));
    }
  }
  __threadfence();
  __syncthreads();
  if (threadIdx.x == 0) {
    int t = atomicAdd(&gcnt[NE], 1);
    if (t == (int)gridDim.x - 1) {            // last block: prefix sum
      int acc = 0;
      for (int k = 0; k < NE; ++k) {
        int ck = atomicAdd(&gcnt[k], 0);      // coherent read
        offs[k] = acc; cur[k] = acc; acc += ck;
      }
      offs[NE] = acc;
    }
  }
}

// ----------------------------------------------------------- sort: scatter
__global__ __launch_bounds__(BLK) void scatter_kernel(
    const int* __restrict__ elem, int N,
    int* __restrict__ cur, int* __restrict__ order) {
  int n = blockIdx.x * BLK + threadIdx.x;
  if (n >= N) return;
  int e = elem[n];
  int lane = threadIdx.x & 63;
#pragma unroll
  for (int k = 0; k < NE; ++k) {
    if (e == k) {
      unsigned long long m = __ballot(1);
      int cnt = __popcll(m);
      int leader = __ffsll((long long)m) - 1;
      int base = 0;
      if (lane == leader) base = atomicAdd(&cur[k], cnt);
      base = __shfl(base, leader);
      int rank = __popcll(m & ((1ull << lane) - 1ull));
      order[base + rank] = n;
    }
  }
}

// ---- build + FULLY (u,v,w)-symmetrize + pack U(x)w tables (one dd/block)
__global__ __launch_bounds__(BLK) void table_kernel(
    const float* __restrict__ U3_0, const float* __restrict__ U2_0,
    const float* __restrict__ U1_0, const float* __restrict__ U3_1,
    const float* __restrict__ U2_1, const float* __restrict__ U1_1,
    const float* __restrict__ w3_0, const float* __restrict__ w2_0,
    const float* __restrict__ w1_0, const float* __restrict__ w3_1,
    const float* __restrict__ w2_1, const float* __restrict__ w1_1,
    float* __restrict__ table) {
  const int b = blockIdx.x;        // e*CCH + c
  const int dd = blockIdx.y;       // 0..3
  const int e = b / CCH, c = b % CCH;
  float* Tg = table + (size_t)b * TGSTR + dd * TSTR;
  __shared__ float Us[U3LDS];      // raw U3 slice [729*K3]
  __shared__ float U2s[324];       // raw U2 slice [81*K2]
  __shared__ float R3[729];        // rect T3
  __shared__ float R2[81];
  __shared__ float R1l[9];
  __shared__ float w3l[12], w2l[4];
  const int tid = threadIdx.x;
  const int d = dd - 1;
  const int K3 = (dd == 0) ? 10 : 12;
  const int K2 = (dd == 0) ? 3 : 4;

  if (dd == 0) {
    for (int i = tid; i < 7290; i += BLK) Us[i] = U3_0[i];
    for (int i = tid; i < 243; i += BLK)  U2s[i] = U2_0[i];
    if (tid < 10) w3l[tid] = w3_0[(e * 10 + tid) * CCH + c];
    else if (tid < 13) w2l[tid - 10] = w2_0[(e * 3 + (tid - 10)) * CCH + c];
    if (tid < 9) R1l[tid] = U1_0[tid] * w1_0[e * CCH + c];
  } else {
    for (int i = tid; i < 8748; i += BLK) Us[i] = U3_1[d * 8748 + i];
    for (int i = tid; i < 324; i += BLK)  U2s[i] = U2_1[d * 324 + i];
    if (tid < 12) w3l[tid] = w3_1[(e * 12 + tid) * CCH + c];
    else if (tid < 16) w2l[tid - 12] = w2_1[(e * 4 + (tid - 12)) * CCH + c];
    if (tid < 9) R1l[tid] = U1_1[d * 9 + tid] * w1_1[e * CCH + c];
  }
  __syncthreads();
  for (int r = tid; r < 729; r += BLK) {
    float acc = 0.f;
    for (int k = 0; k < K3; ++k) acc += Us[r * K3 + k] * w3l[k];
    R3[r] = acc;
  }
  for (int q = tid; q < 81; q += BLK) {
    float acc = 0.f;
    for (int k = 0; k < K2; ++k) acc += U2s[q * K2 + k] * w2l[k];
    R2[q] = acc;
  }
  __syncthreads();
  // pack: Horner consumption order. Per u: [T1s[u], then per v=u..8:
  //   [T2s[u][v], S3s[u][v][w] for w=v..8]].  Per-u size = (10-u)(11-u)/2.
  for (int i = tid; i < TSTR; i += BLK) {
    float val = 0.f;
    if (i < 219) {
      int rem = i, u = 0;
      while (rem >= (10 - u) * (11 - u) / 2) {
        rem -= (10 - u) * (11 - u) / 2; ++u;
      }
      if (rem == 0) {
        val = R1l[u];
      } else {
        rem -= 1;
        int v = u;
        while (rem >= 10 - v) { rem -= 10 - v; ++v; }
        if (rem == 0) {
          val = (u == v) ? R2[u * 9 + v] : R2[u * 9 + v] + R2[v * 9 + u];
        } else {
          int w = v + (rem - 1);
          if (u == v && v == w)
            val = R3[(u * 9 + u) * 9 + u];
          else if (u == v)
            val = R3[(u * 9 + u) * 9 + w] + R3[(u * 9 + w) * 9 + u] +
                  R3[(w * 9 + u) * 9 + u];
          else if (v == w)
            val = R3[(u * 9 + v) * 9 + v] + R3[(v * 9 + u) * 9 + v] +
                  R3[(v * 9 + v) * 9 + u];
          else
            val = R3[(u * 9 + v) * 9 + w] + R3[(u * 9 + w) * 9 + v] +
                  R3[(v * 9 + u) * 9 + w] + R3[(v * 9 + w) * 9 + u] +
                  R3[(w * 9 + u) * 9 + v] + R3[(w * 9 + v) * 9 + u];
        }
      }
    }
    Tg[i] = val;
  }
}

// --- symmetric contraction: triangular Horner over fully-sym table.
//     thread = 1 node x 1 channel; no LDS; cb via uniform s_load.
//     blockIdx.y = global chunk -> (e, segment) via offs (compact grid).
__global__ __launch_bounds__(BLK, 8) void contract_kernel(
    const float* __restrict__ feats, const float* __restrict__ table,
    const int* __restrict__ order, const int* __restrict__ offs,
    float* __restrict__ tmp, int NPAD) {
  const int c = blockIdx.x;                   // 0..127
  // map global chunk -> (element e, node range) ; wave-uniform
  int rem = blockIdx.y;
  int e = -1, pbase = 0, segend = 0;
#pragma unroll
  for (int k = 0; k < NE; ++k) {
    int st = offs[k], en = offs[k + 1];
    int nc = (en - st + BLK - 1) >> 8;        // chunks in segment k (BLK=256)
    if (e < 0) {
      if (rem < nc) { e = k; pbase = st + rem * BLK; segend = en; }
      else rem -= nc;
    }
  }
  if (e < 0) return;                          // slack chunk

  const int p = pbase + threadIdx.x;
  const bool valid = (p < segend);
  const int n = order[valid ? p : (segend - 1)];  // clamp: stay in-bounds

  float tf[LDIM];
  {
    const float* xp = feats + ((size_t)n * CCH + c) * LDIM;
#pragma unroll
    for (int q = 0; q < LDIM; ++q) tf[q] = xp[q];
  }

  const float* Tc = table + (size_t)(e * CCH + c) * TGSTR;

#pragma unroll 1
  for (int dd = 0; dd < 4; ++dd) {
    // wave-uniform address (blockIdx/dd only) -> s_load (SMEM path)
    const float* B = Tc + dd * TSTR;
    int idx = 0;                              // folds to constants on unroll
    float acc = 0.f;
#pragma unroll
    for (int u = 0; u < 9; ++u) {
      float inner = B[idx++];                 // T1s[u]
#pragma unroll
      for (int v = u; v < 9; ++v) {
        float Hv = B[idx++];                  // T2sym[u][v]
#pragma unroll
        for (int w = v; w < 9; ++w)
          Hv = fmaf(B[idx++], tf[w], Hv);
        inner = fmaf(Hv, tf[v], inner);
      }
      acc = fmaf(inner, tf[u], acc);
    }
    if (valid) tmp[((size_t)dd * CCH + c) * NPAD + p] = acc;
  }
}

// ------------- o3.Linear + residual: LDS-tiled GEMM, W double-buffered via
//               global_load_lds (compiler-proof pipeline)
#define NB 16                 // nodes per block
// LDS float map: A[0,8192) = A[dd][ci][16j] | Wbuf0 [8192,12288) | Wbuf1 [12288,16384)
// Each Wbuf: 16 ci x (W0row[128] | W1row[128]) -> W0 slice [0,2048), W1 slice [2048,4096)
__global__ __launch_bounds__(BLK, 2) void linear_kernel(
    const float* __restrict__ tmp, const float* __restrict__ W0,
    const float* __restrict__ W1, const float* __restrict__ sc,
    const int* __restrict__ order, float* __restrict__ out, int N, int NPAD) {
  const int p0 = blockIdx.x * NB;
  const int t = threadIdx.x;
  const int wave = t >> 6, lane = t & 63;
  __shared__ __align__(16) float SU[16384];   // 64 KB

  // ---- phase 1: stage A[dd][ci][j] = tmp[dd][ci][p0+j], coalesced float4
#pragma unroll
  for (int k = 0; k < 8; ++k) {
    int f = t + k * BLK;               // float4 index 0..2047
    int dd = f >> 9, r = f & 511;
    int ci = r >> 2, q = r & 3;
    float4 v = *(const float4*)(tmp + (size_t)(dd * CCH + ci) * NPAD + p0 + q * 4);
    *(float4*)(SU + dd * 2048 + ci * 16 + q * 4) = v;
  }
  // ---- issue W chunk 0 direct-to-LDS (wave w: two 1KB spans per matrix)
  {
    const int fo0 = wave * 512 + lane * 4;    // float offsets, 16B per lane
    const int fo1 = fo0 + 256;
    __builtin_amdgcn_global_load_lds(W0 + fo0, &SU[8192 + fo0], 16, 0, 0);
    __builtin_amdgcn_global_load_lds(W0 + fo1, &SU[8192 + fo1], 16, 0, 0);
    __builtin_amdgcn_global_load_lds(W1 + fo0, &SU[8192 + 2048 + fo0], 16, 0, 0);
    __builtin_amdgcn_global_load_lds(W1 + fo1, &SU[8192 + 2048 + fo1], 16, 0, 0);
  }
  __syncthreads();                     // drains vmcnt(0): A + chunk0 ready

  // ---- phase 2: thread = (node-pair j2 0..7, co-quad o 0..31)
  const int j2 = t & 7;
  const int o = t >> 3;
  float acc[2][4][4];                  // [node jj][dd][k]
#pragma unroll
  for (int jj = 0; jj < 2; ++jj)
#pragma unroll
    for (int dd = 0; dd < 4; ++dd)
#pragma unroll
      for (int k = 0; k < 4; ++k) acc[jj][dd][k] = 0.f;

#pragma unroll 1
  for (int kk = 0; kk < 8; ++kk) {
    if (kk < 7) {                      // issue chunk kk+1 into other buf
      const int wb = 8192 + ((kk + 1) & 1) * 4096;
      const float* s0 = W0 + (kk + 1) * 2048;
      const float* s1 = W1 + (kk + 1) * 2048;
      const int fo0 = wave * 512 + lane * 4;
      const int fo1 = fo0 + 256;
      __builtin_amdgcn_global_load_lds(s0 + fo0, &SU[wb + fo0], 16, 0, 0);
      __builtin_amdgcn_global_load_lds(s0 + fo1, &SU[wb + fo1], 16, 0, 0);
      __builtin_amdgcn_global_load_lds(s1 + fo0, &SU[wb + 2048 + fo0], 16, 0, 0);
      __builtin_amdgcn_global_load_lds(s1 + fo1, &SU[wb + 2048 + fo1], 16, 0, 0);
    }
    const int wb = 8192 + (kk & 1) * 4096;
#pragma unroll
    for (int cl = 0; cl < 16; ++cl) {
      const int ci = kk * 16 + cl;
      const float4 wa = *(const float4*)(SU + wb + cl * 128 + o * 4);
      const float4 wc = *(const float4*)(SU + wb + 2048 + cl * 128 + o * 4);
      float av[4][2];
#pragma unroll
      for (int dd = 0; dd < 4; ++dd) {
        av[dd][0] = SU[dd * 2048 + ci * 16 + j2];
        av[dd][1] = SU[dd * 2048 + ci * 16 + j2 + 8];
      }
#pragma unroll
      for (int jj = 0; jj < 2; ++jj) {
        acc[jj][0][0] = fmaf(av[0][jj], wa.x, acc[jj][0][0]);
        acc[jj][0][1] = fmaf(av[0][jj], wa.y, acc[jj][0][1]);
        acc[jj][0][2] = fmaf(av[0][jj], wa.z, acc[jj][0][2]);
        acc[jj][0][3] = fmaf(av[0][jj], wa.w, acc[jj][0][3]);
#pragma unroll
        for (int d = 1; d < 4; ++d) {
          acc[jj][d][0] = fmaf(av[d][jj], wc.x, acc[jj][d][0]);
          acc[jj][d][1] = fmaf(av[d][jj], wc.y, acc[jj][d][1]);
          acc[jj][d][2] = fmaf(av[d][jj], wc.z, acc[jj][d][2]);
          acc[jj][d][3] = fmaf(av[d][jj], wc.w, acc[jj][d][3]);
        }
      }
    }
    __syncthreads();   // chunk kk+1 drained (vmcnt(0)); buf kk free for kk+2
  }

  // ---- phase 3: assemble output rows in LDS (SU reused as S[16][516])
  const float s = 0.08838834764831843f;        // 1/sqrt(128)
#pragma unroll
  for (int jj = 0; jj < 2; ++jj) {
    float* Sj = SU + (j2 + jj * 8) * 516;
#pragma unroll
    for (int k = 0; k < 4; ++k) {
      int co = o * 4 + k;
      Sj[co]               = acc[jj][0][k] * s;
      Sj[CCH + co * 3 + 0] = acc[jj][1][k] * s;
      Sj[CCH + co * 3 + 1] = acc[jj][2][k] * s;
      Sj[CCH + co * 3 + 2] = acc[jj][3][k] * s;
    }
  }
  __syncthreads();

  // ---- phase 4: sc + write, full 512-float rows, float4-coalesced
  const int f = t & 127;               // float4 index within row
  const int jj4 = t >> 7;
#pragma unroll 1
  for (int jr = jj4; jr < NB; jr += 2) {
    int p = p0 + jr;
    if (p < N) {
      int n = order[p];
      float4 sv = ((const float4*)(sc + (size_t)n * 512))[f];
      float4 ov = ((const float4*)(SU + jr * 516))[f];
      ov.x += sv.x; ov.y += sv.y; ov.z += sv.z; ov.w += sv.w;
      ((float4*)(out + (size_t)n * 512))[f] = ov;
    }
  }
}

// -------------------------------------------------------------------- launch
extern "C" void kernel_launch(void* const* d_in, const int* in_sizes, int n_in,
                              void* d_out, int out_size, void* d_ws, size_t ws_size,
                              hipStream_t stream) {
  const float* feats = (const float*)d_in[0];
  const float* attrs = (const float*)d_in[1];
  const float* sc    = (const float*)d_in[2];
  const float* U3_0  = (const float*)d_in[3];
  const float* U2_0  = (const float*)d_in[4];
  const float* U1_0  = (const float*)d_in[5];
  const float* w3_0  = (const float*)d_in[6];
  const float* w2_0  = (const float*)d_in[7];
  const float* w1_0  = (const float*)d_in[8];
  const float* U3_1  = (const float*)d_in[9];
  const float* U2_1  = (const float*)d_in[10];
  const float* U1_1  = (const float*)d_in[11];
  const float* w3_1  = (const float*)d_in[12];
  const float* w2_1  = (const float*)d_in[13];
  const float* w1_1  = (const float*)d_in[14];
  const float* W0    = (const float*)d_in[15];
  const float* W1    = (const float*)d_in[16];

  const int N = in_sizes[0] / (CCH * LDIM);     // 10000
  const int NPAD = ((N + 15) & ~15) + 16;

  // ws (floats): table[5*128*TGSTR] | tmp[4*C][NPAD] | order elem offs(8) cur(8) gcnt(8)
  float* table = (float*)d_ws;
  float* tmp   = table + (size_t)NE * CCH * TGSTR;
  int*   order = (int*)(tmp + (size_t)4 * CCH * NPAD);
  int*   elem  = order + N;
  int*   offs  = elem + N;
  int*   cur   = offs + 8;
  int*   gcnt  = cur + 8;                       // gcnt[0..4], gcnt[5]=done
  float* out   = (float*)d_out;

  hipMemsetAsync(gcnt, 0, 8 * sizeof(int), stream);

  const int nblk = (N + BLK - 1) / BLK;
  count_offs_kernel<<<dim3(nblk), dim3(BLK), 0, stream>>>(
      attrs, N, elem, gcnt, offs, cur);
  scatter_kernel<<<dim3(nblk), dim3(BLK), 0, stream>>>(elem, N, cur, order);

  table_kernel<<<dim3(NE * CCH, 4), dim3(BLK), 0, stream>>>(
      U3_0, U2_0, U1_0, U3_1, U2_1, U1_1,
      w3_0, w2_0, w1_0, w3_1, w2_1, w1_1, table);

  // compact chunk grid: sum over e of ceil(cnt_e/BLK) <= N/BLK + NE
  const int chunksMax = (N + BLK - 1) / BLK + NE;
  contract_kernel<<<dim3(CCH, chunksMax), dim3(BLK), 0, stream>>>(
      feats, table, order, offs, tmp, NPAD);

  linear_kernel<<<dim3((N + NB - 1) / NB), dim3(BLK), 0, stream>>>(
      tmp, W0, W1, sc, order, out, N, NPAD);
}